// Round 15
// baseline (268.016 us; speedup 1.0000x reference)
//
#include <hip/hip_runtime.h>

// ---------------- problem constants ----------------
#define F_BINS 257
#define NCH    8
#define NSRC   2
#define KW     5
#define HCH    32
#define TLEN   2000
#define BATCH  4

// ---------------- tiling ----------------
#define TT      112
#define NTILES  18          // 18*112 = 2016 >= 2000
#define NK      (BATCH * F_BINS)        // 1028 (b,f) pairs
#define NRANK   ((NK + 7) / 8)          // 129
#define GRID    (NRANK * NTILES * 8)    // 18576

// LDS layout (bytes): H1 at 0; X at 16384; H2 ALIASES X (X dead after L1 —
// phase M reads x from registers). h3 aliases H1 (dead after L2 reads).
#define XSTRIDE 24
#define XCOLS   132                            // halo 10/10
#define HWIN    128                            // h1/h2 window: [t0-8, t0+120)
#define HSZ     (HWIN * 64 * 2)                // 16384 B
#define H1OFF   0
#define XOFF    HSZ                            // 16384
#define H2OFF   HSZ                            // aliases X
#define H3OFF   0                              // aliases H1
#define SMEM_BYTES (2 * HSZ)                   // 32768 B -> 4 blocks/CU
#define H3STRIDE 40                            // halves per col (32 used + pad)

// packed weight fragments: [f][frag*2+mw][lane] of half8 (16B each)
#define NFRAG   36
#define PW_HALF8_PER_F (NFRAG * 2 * 64)
#define PW_BYTES ((size_t)F_BINS * PW_HALF8_PER_F * 16)   // ~18.9 MB

typedef _Float16 half8  __attribute__((ext_vector_type(8)));
typedef __fp16   pk16x2 __attribute__((ext_vector_type(2)));   // cvt_pkrtz result type
typedef __fp16   pk16x4 __attribute__((ext_vector_type(4)));   // merged 8B epi store
typedef float    f32x4  __attribute__((ext_vector_type(4)));

#define MFMA16(a, b, c) __builtin_amdgcn_mfma_f32_16x16x32_f16(a, b, c, 0, 0, 0)

// frag ids: a1[hr][p] = hr*3+p (0..5); a2[w][hr][kk] = 6+w*4+hr*2+kk (6..25);
//           a3[w][kk] = 26+w*2+kk (26..35)
__device__ __forceinline__ half8 gather_frag(
    int f, int frag, int mw, int lane,
    const float* __restrict__ Wr1, const float* __restrict__ Wi1,
    const float* __restrict__ Wr2, const float* __restrict__ Wi2,
    const float* __restrict__ Wr3, const float* __restrict__ Wi3)
{
    const int g = lane >> 4, r16 = lane & 15;
    half8 v;
    if (frag < 6) {
        int hr = frag / 3, p = frag % 3;
        int tap = 2 * p + (g >> 1);
        #pragma unroll
        for (int j = 0; j < 8; ++j) {
            float val = 0.f;
            if (tap < KW) {
                long idx = (((long)f * HCH + hr * 16 + r16) * NCH + j) * KW + tap;
                if (mw == 0) val = (g & 1) ? -Wi1[idx] : Wr1[idx];
                else         val = (g & 1) ?  Wr1[idx] : Wi1[idx];
            }
            v[j] = (_Float16)val;
        }
    } else if (frag < 26) {
        int u = frag - 6;
        int w = u >> 2, hr = (u >> 1) & 1, kk = u & 1;
        #pragma unroll
        for (int j = 0; j < 8; ++j) {
            int c = g * 8 + j;
            long idx = (((long)f * HCH + hr * 16 + r16) * HCH + c) * KW + w;
            float val;
            if (mw == 0) val = kk ? -Wi2[idx] : Wr2[idx];
            else         val = kk ?  Wr2[idx] : Wi2[idx];
            v[j] = (_Float16)val;
        }
    } else {
        int u = frag - 26;
        int w = u >> 1, kk = u & 1;
        #pragma unroll
        for (int j = 0; j < 8; ++j) {
            int c = g * 8 + j;
            long idx = (((long)f * (NCH * NSRC) + r16) * HCH + c) * KW + w;
            float val;
            if (mw == 0) val = kk ? -Wi3[idx] : Wr3[idx];
            else         val = kk ?  Wr3[idx] : Wi3[idx];
            v[j] = (_Float16)val;
        }
    }
    return v;
}

__global__ __launch_bounds__(256) void repack_kernel(
    const float* __restrict__ Wr1, const float* __restrict__ Wi1,
    const float* __restrict__ Wr2, const float* __restrict__ Wi2,
    const float* __restrict__ Wr3, const float* __restrict__ Wi3,
    _Float16* __restrict__ pw)
{
    const int bid  = blockIdx.x;
    const int f    = bid >> 2;
    const int part = bid & 3;
    const int lane = threadIdx.x & 63;
    const int q    = threadIdx.x >> 6;
    half8* pwv = (half8*)pw;
    for (int u = part * 18 + q; u < part * 18 + 18; u += 4) {
        int frag = u >> 1, mw = u & 1;
        half8 v = gather_frag(f, frag, mw, lane, Wr1, Wi1, Wr2, Wi2, Wr3, Wi3);
        pwv[((size_t)f * (NFRAG * 2) + u) * 64 + lane] = v;
    }
}

template<bool PACKED>
__global__ __launch_bounds__(256, 4) void cddcnn_mfma_kernel(
    const float* __restrict__ x,
    const float* __restrict__ Wr1, const float* __restrict__ Wi1,
    const float* __restrict__ Wr2, const float* __restrict__ Wi2,
    const float* __restrict__ Wr3, const float* __restrict__ Wi3,
    float* __restrict__ out, const _Float16* __restrict__ pw)
{
    __shared__ __align__(16) char sm[SMEM_BYTES];

    const int tid  = threadIdx.x;
    const int lane = tid & 63;
    const int wv   = tid >> 6;      // wave owns col-blocks {2wv, 2wv+1}
    const int g    = lane >> 4;
    const int r16  = lane & 15;

    // XCD swizzle: all 18 tiles of one k=(b,f) on xcd=k&7 (weights L2-resident)
    const int bid  = blockIdx.x;
    const int xcd  = bid & 7;
    const int rt   = bid >> 3;
    const int tl   = rt % NTILES;
    const int k    = (rt / NTILES) * 8 + xcd;
    if (k >= NK) return;
    const int f    = k % F_BINS;
    const int b    = k / F_BINS;
    const int t0   = tl * TT;
    const bool interior = (tl >= 1) && (tl <= 16);

    const int colb = wv * 32 + r16;      // own col at cbi=0 (+ cbi*16)

    const half8* pwb = PACKED ? ((const half8*)pw) + (size_t)f * PW_HALF8_PER_F + lane
                              : nullptr;
    #define LOADFRAG2(fr, mww) (PACKED ? pwb[((fr) * 2 + (mww)) * 64] \
                  : gather_frag(f, (fr), (mww), lane, Wr1, Wi1, Wr2, Wi2, Wr3, Wi3))

    const long xr_base = ((long)(b * 2 * F_BINS + f) * NCH) * TLEN;
    const long xi_base = ((long)(b * 2 * F_BINS + F_BINS + f) * NCH) * TLEN;

    // ---- Phase X: stage x tile as fp16 [132 cols][16 ch] ----
    // thread-per-col: 16 coalesced loads -> 2x ds_write_b128 (conflict-free).
    // pkr/pki HELD in registers through phase M (8 VGPRs).
    half8 pkr = {}, pki = {};
    if (tid < XCOLS) {
        int t = t0 - 10 + tid;
        bool ok = (t >= 0) && (t < TLEN);
        #pragma unroll
        for (int c = 0; c < 8; ++c) {
            float vr = ok ? x[xr_base + (long)c * TLEN + t] : 0.f;
            float vi = ok ? x[xi_base + (long)c * TLEN + t] : 0.f;
            pkr[c] = (_Float16)vr;
            pki[c] = (_Float16)vi;
        }
        *(half8*)(sm + XOFF + tid * (XSTRIDE * 2))      = pkr;
        *(half8*)(sm + XOFF + tid * (XSTRIDE * 2) + 16) = pki;
    }

    // ---- a1 frags, both mw (latency hidden under staging + barrier) ----
    half8 a1[2][2][3];   // [mw][hr][p]
    #pragma unroll
    for (int mw = 0; mw < 2; ++mw)
    #pragma unroll
    for (int hr = 0; hr < 2; ++hr)
    #pragma unroll
    for (int p = 0; p < 3; ++p)
        a1[mw][hr][p] = LOADFRAG2(hr * 3 + p, mw);
    __syncthreads();

    const int Xc = (r16 & 7) << 4;       // swizzle XOR ((col&7) == (r16&7))
    int woff64[2][2];                    // epi byte offset: (mw*64+hr*32+g*8)^Xc
    #pragma unroll
    for (int mw = 0; mw < 2; ++mw)
    #pragma unroll
    for (int hr = 0; hr < 2; ++hr)
        woff64[mw][hr] = ((mw * 64 + hr * 32 + g * 8) ^ Xc);

    half8 a2n[2][2][2];  // rolling next-w frags [mw][hr][kk]

    // ---- Phase L1: h1 = relu(cconv(x, W1)), 128-col window, 2 cb/wave ----
    {
        f32x4 acc[2][2][2] = {};   // [cbi][mw][hr]
        const char* xb = sm + XOFF + (colb * XSTRIDE + (g & 1) * 8) * 2;
        #pragma unroll
        for (int p = 0; p < 3; ++p) {
            int tap = 2 * p + (g >> 1);
            if (tap > 4) tap = 4;          // A is zero for these groups
            const char* xbp = xb + tap * (XSTRIDE * 2);
            #pragma unroll
            for (int cbi = 0; cbi < 2; ++cbi) {
                const half8 bf = *(const half8*)(xbp + cbi * (16 * XSTRIDE * 2));
                #pragma unroll
                for (int mw = 0; mw < 2; ++mw)
                #pragma unroll
                for (int hr = 0; hr < 2; ++hr)
                    acc[cbi][mw][hr] = MFMA16(a1[mw][hr][p], bf, acc[cbi][mw][hr]);
            }
        }

        // prefetch a2 w=0 (hidden under epilogue + barrier)
        #pragma unroll
        for (int mw = 0; mw < 2; ++mw)
        #pragma unroll
        for (int hr = 0; hr < 2; ++hr)
        #pragma unroll
        for (int kk = 0; kk < 2; ++kk)
            a2n[mw][hr][kk] = LOADFRAG2(6 + hr * 2 + kk, mw);

        // epilogue -> H1 (merged 8B writes, all 4 row-tiles per col)
        char* wb = sm + H1OFF + colb * 128;
        #pragma unroll
        for (int cbi = 0; cbi < 2; ++cbi) {
            int t = t0 - 8 + colb + cbi * 16;
            bool ok = interior || ((t >= 0) && (t < TLEN));
            #pragma unroll
            for (int mw = 0; mw < 2; ++mw)
            #pragma unroll
            for (int hr = 0; hr < 2; ++hr) {
                float v0 = ok ? fmaxf(acc[cbi][mw][hr][0], 0.f) : 0.f;
                float v1 = ok ? fmaxf(acc[cbi][mw][hr][1], 0.f) : 0.f;
                float v2 = ok ? fmaxf(acc[cbi][mw][hr][2], 0.f) : 0.f;
                float v3 = ok ? fmaxf(acc[cbi][mw][hr][3], 0.f) : 0.f;
                pk16x2 lo = __builtin_amdgcn_cvt_pkrtz(v0, v1);
                pk16x2 hi = __builtin_amdgcn_cvt_pkrtz(v2, v3);
                pk16x4 hv; hv[0] = lo[0]; hv[1] = lo[1]; hv[2] = hi[0]; hv[3] = hi[1];
                *(pk16x4*)(wb + cbi * 2048 + woff64[mw][hr]) = hv;
            }
        }
    }
    __syncthreads();

    half8 a3n[2][2];     // rolling next-w frags [mw][kk]

    // ---- Phase L2: h2 = relu(cconv(h1, W2)); write H2 (aliases dead X) ----
    {
        f32x4 acc[2][2][2] = {};   // [cbi][mw][hr]
        #pragma unroll
        for (int w = 0; w < KW; ++w) {
            half8 a2c[2][2][2];
            #pragma unroll
            for (int mw = 0; mw < 2; ++mw)
            #pragma unroll
            for (int hr = 0; hr < 2; ++hr)
            #pragma unroll
            for (int kk = 0; kk < 2; ++kk)
                a2c[mw][hr][kk] = a2n[mw][hr][kk];
            if (w < 4) {
                #pragma unroll
                for (int mw = 0; mw < 2; ++mw)
                #pragma unroll
                for (int hr = 0; hr < 2; ++hr)
                #pragma unroll
                for (int kk = 0; kk < 2; ++kk)
                    a2n[mw][hr][kk] = LOADFRAG2(6 + (w + 1) * 4 + hr * 2 + kk, mw);
            }

            const int sc0 = colb + w - 2;
            const int vb  = sc0 * 128 + ((g * 16) ^ ((sc0 & 7) << 4));
            #pragma unroll
            for (int kk = 0; kk < 2; ++kk) {
                const char* rb = sm + H1OFF + (kk ? (vb ^ 64) : vb);
                #pragma unroll
                for (int cbi = 0; cbi < 2; ++cbi) {
                    const half8 bf = *(const half8*)(rb + cbi * 2048);
                    #pragma unroll
                    for (int mw = 0; mw < 2; ++mw)
                    #pragma unroll
                    for (int hr = 0; hr < 2; ++hr)
                        acc[cbi][mw][hr] = MFMA16(a2c[mw][hr][kk], bf, acc[cbi][mw][hr]);
                }
            }
        }

        // prefetch a3 w=0
        #pragma unroll
        for (int mw = 0; mw < 2; ++mw)
        #pragma unroll
        for (int kk = 0; kk < 2; ++kk)
            a3n[mw][kk] = LOADFRAG2(26 + kk, mw);

        char* wb = sm + H2OFF + colb * 128;
        #pragma unroll
        for (int cbi = 0; cbi < 2; ++cbi) {
            int t = t0 - 8 + colb + cbi * 16;
            bool ok = interior || ((t >= 0) && (t < TLEN));
            #pragma unroll
            for (int mw = 0; mw < 2; ++mw)
            #pragma unroll
            for (int hr = 0; hr < 2; ++hr) {
                float v0 = ok ? fmaxf(acc[cbi][mw][hr][0], 0.f) : 0.f;
                float v1 = ok ? fmaxf(acc[cbi][mw][hr][1], 0.f) : 0.f;
                float v2 = ok ? fmaxf(acc[cbi][mw][hr][2], 0.f) : 0.f;
                float v3 = ok ? fmaxf(acc[cbi][mw][hr][3], 0.f) : 0.f;
                pk16x2 lo = __builtin_amdgcn_cvt_pkrtz(v0, v1);
                pk16x2 hi = __builtin_amdgcn_cvt_pkrtz(v2, v3);
                pk16x4 hv; hv[0] = lo[0]; hv[1] = lo[1]; hv[2] = hi[0]; hv[3] = hi[1];
                *(pk16x4*)(wb + cbi * 2048 + woff64[mw][hr]) = hv;
            }
        }
    }
    __syncthreads();

    // ---- Phase L3: h3 = cconv(h2, W3) (no relu), 112 cols (7 cb: 2,2,2,1) ----
    {
        const int ncb3 = (wv == 3) ? 1 : 2;
        f32x4 acc3[2][2] = {};   // [cbi][mw]
        #pragma unroll
        for (int w = 0; w < KW; ++w) {
            half8 a3c[2][2];
            #pragma unroll
            for (int mw = 0; mw < 2; ++mw)
            #pragma unroll
            for (int kk = 0; kk < 2; ++kk)
                a3c[mw][kk] = a3n[mw][kk];
            if (w < 4) {
                #pragma unroll
                for (int mw = 0; mw < 2; ++mw)
                #pragma unroll
                for (int kk = 0; kk < 2; ++kk)
                    a3n[mw][kk] = LOADFRAG2(26 + (w + 1) * 2 + kk, mw);
            }

            const int sc0 = colb + 6 + w;
            const int vb  = sc0 * 128 + ((g * 16) ^ ((sc0 & 7) << 4));
            #pragma unroll
            for (int kk = 0; kk < 2; ++kk) {
                const char* rb = sm + H2OFF + (kk ? (vb ^ 64) : vb);
                #pragma unroll
                for (int cbi = 0; cbi < 2; ++cbi) {
                    if (cbi < ncb3) {
                        const half8 bf = *(const half8*)(rb + cbi * 2048);
                        #pragma unroll
                        for (int mw = 0; mw < 2; ++mw)
                            acc3[cbi][mw] = MFMA16(a3c[mw][kk], bf, acc3[cbi][mw]);
                    }
                }
            }
        }
        char* wb3 = sm + H3OFF + colb * (H3STRIDE * 2) + g * 8;
        #pragma unroll
        for (int cbi = 0; cbi < 2; ++cbi) {
            if (cbi < ncb3) {
                #pragma unroll
                for (int mw = 0; mw < 2; ++mw) {
                    pk16x2 lo = __builtin_amdgcn_cvt_pkrtz(acc3[cbi][mw][0], acc3[cbi][mw][1]);
                    pk16x2 hi = __builtin_amdgcn_cvt_pkrtz(acc3[cbi][mw][2], acc3[cbi][mw][3]);
                    pk16x4 hv; hv[0] = lo[0]; hv[1] = lo[1]; hv[2] = hi[0]; hv[3] = hi[1];
                    *(pk16x4*)(wb3 + cbi * (16 * H3STRIDE * 2) + mw * 32) = hv;
                }
            }
        }
    }
    __syncthreads();

    // ---- Phase M: mask multiply + channel reduce + store ----
    // Thread tid (10..121) owns col = tid-10 (matches its staged pkr/pki).
    {
        int col = tid - 10;
        if (col >= 0 && col < TT) {
            int t = t0 + col;
            if (t < TLEN) {
                half8 h3q[4];
                #pragma unroll
                for (int q = 0; q < 4; ++q)
                    h3q[q] = *(const half8*)(sm + H3OFF + col * (H3STRIDE * 2) + q * 16);
                float Yr[2] = {0.f, 0.f}, Yi[2] = {0.f, 0.f};
                #pragma unroll
                for (int c = 0; c < NCH; ++c) {
                    float vr = (float)pkr[c];
                    float vi = (float)pki[c];
                    #pragma unroll
                    for (int s = 0; s < NSRC; ++s) {
                        int o = 2 * c + s;
                        float hr = (c < 4) ? (float)h3q[0][o] : (float)h3q[1][o - 8];
                        float hi = (c < 4) ? (float)h3q[2][o] : (float)h3q[3][o - 8];
                        Yr[s] += vr * hr - vi * hi;
                        Yi[s] += vr * hi + vi * hr;
                    }
                }
                #pragma unroll
                for (int s = 0; s < NSRC; ++s) {
                    out[((long)(b * 2 * F_BINS + f) * NSRC + s) * TLEN + t]          = Yr[s];
                    out[((long)(b * 2 * F_BINS + F_BINS + f) * NSRC + s) * TLEN + t] = Yi[s];
                }
            }
        }
    }
}

extern "C" void kernel_launch(void* const* d_in, const int* in_sizes, int n_in,
                              void* d_out, int out_size, void* d_ws, size_t ws_size,
                              hipStream_t stream) {
    const float* x   = (const float*)d_in[0];
    const float* Wr1 = (const float*)d_in[1];
    const float* Wi1 = (const float*)d_in[2];
    const float* Wr2 = (const float*)d_in[3];
    const float* Wi2 = (const float*)d_in[4];
    const float* Wr3 = (const float*)d_in[5];
    const float* Wi3 = (const float*)d_in[6];
    float* out = (float*)d_out;

    dim3 block(256);
    dim3 grid(GRID);
    if (ws_size >= PW_BYTES) {
        _Float16* pw = (_Float16*)d_ws;
        repack_kernel<<<F_BINS * 4, block, 0, stream>>>(Wr1, Wi1, Wr2, Wi2, Wr3, Wi3, pw);
        cddcnn_mfma_kernel<true><<<grid, block, 0, stream>>>(
            x, Wr1, Wi1, Wr2, Wi2, Wr3, Wi3, out, pw);
    } else {
        cddcnn_mfma_kernel<false><<<grid, block, 0, stream>>>(
            x, Wr1, Wi1, Wr2, Wi2, Wr3, Wi3, out, nullptr);
    }
}